// Round 1
// baseline (634.382 us; speedup 1.0000x reference)
//
#include <hip/hip_runtime.h>
#include <hip/hip_bf16.h>

// CausalSelfAttention: x@Wq^T,Wk^T,Wv^T -> heads -> causal flash attn -> @Wp^T + bp
// B=4 T=2048 C=1024 H=16 HD=64. All matmuls via mfma_f32_16x16x32_bf16 (fp32 accum).

using bf16   = __bf16;
using bf16x8 = __attribute__((ext_vector_type(8))) __bf16;
using bf16x4 = __attribute__((ext_vector_type(4))) __bf16;
using f32x4  = __attribute__((ext_vector_type(4))) float;

#define MFMA16(a, b, c) __builtin_amdgcn_mfma_f32_16x16x32_bf16((a), (b), (c), 0, 0, 0)

// ---------------------------------------------------------------------------
// Kernel 1: fused QKV projection GEMM.  M=8192 (b,t), N=3072 (3 x 1024), K=1024.
// C[m][n] = sum_k x[m][k] * W[n][k]  (+bias). Output scattered to [B,H,T,64] bf16.
// 128x128 tile, 4 waves (2x2), each wave 64x64 = 4x4 fragments of 16x16.
// ---------------------------------------------------------------------------
__global__ __launch_bounds__(256) void qkv_gemm(
    const float* __restrict__ x,
    const float* __restrict__ Wq, const float* __restrict__ Wk, const float* __restrict__ Wv,
    const float* __restrict__ bq, const float* __restrict__ bk, const float* __restrict__ bv,
    bf16* __restrict__ qws, bf16* __restrict__ kws, bf16* __restrict__ vws)
{
    __shared__ bf16 As[128][72];   // pad to 72 (144B rows = 36 banks -> <=2-way, free)
    __shared__ bf16 Bs[128][72];
    const int tid  = threadIdx.x;
    const int lane = tid & 63;
    const int wid  = tid >> 6;
    const int bm   = blockIdx.x;           // 64 row tiles
    const int bn   = blockIdx.y;           // 24 col tiles (3 matrices x 8)
    const int widx  = bn >> 3;
    const int nbase = (bn & 7) << 7;
    const float* __restrict__ W    = (widx == 0) ? Wq : (widx == 1) ? Wk : Wv;
    const float* __restrict__ bias = (widx == 0) ? bq : (widx == 1) ? bk : bv;
    bf16* __restrict__ outp        = (widx == 0) ? qws : (widx == 1) ? kws : vws;

    const int wr   = (wid >> 1) << 6;      // wave row offset in tile
    const int wc   = (wid & 1) << 6;       // wave col offset in tile
    const int lr16 = lane & 15;
    const int lk8  = (lane >> 4) << 3;

    f32x4 acc[4][4];
#pragma unroll
    for (int m = 0; m < 4; ++m)
#pragma unroll
        for (int n = 0; n < 4; ++n)
            acc[m][n] = (f32x4){0.f, 0.f, 0.f, 0.f};

    for (int kt = 0; kt < 16; ++kt) {      // K loop, BK=64
        const int k0 = kt << 6;
        __syncthreads();
        // stage A tile (x) 128x64 fp32 -> bf16
#pragma unroll
        for (int i = 0; i < 8; ++i) {
            const int f   = tid + (i << 8);      // 0..2047 float4 chunks
            const int row = f >> 4;
            const int c4  = (f & 15) << 2;
            const float4 v = *(const float4*)(x + (size_t)(bm * 128 + row) * 1024 + k0 + c4);
            bf16x4 pk = {(bf16)v.x, (bf16)v.y, (bf16)v.z, (bf16)v.w};
            *(bf16x4*)(&As[row][c4]) = pk;
        }
        // stage B tile (W rows nbase..nbase+127) 128x64 fp32 -> bf16
#pragma unroll
        for (int i = 0; i < 8; ++i) {
            const int f   = tid + (i << 8);
            const int row = f >> 4;
            const int c4  = (f & 15) << 2;
            const float4 v = *(const float4*)(W + (size_t)(nbase + row) * 1024 + k0 + c4);
            bf16x4 pk = {(bf16)v.x, (bf16)v.y, (bf16)v.z, (bf16)v.w};
            *(bf16x4*)(&Bs[row][c4]) = pk;
        }
        __syncthreads();
#pragma unroll
        for (int ks = 0; ks < 2; ++ks) {
            bf16x8 af[4], bfr[4];
#pragma unroll
            for (int m = 0; m < 4; ++m)
                af[m] = *(const bf16x8*)(&As[wr + m * 16 + lr16][ks * 32 + lk8]);
#pragma unroll
            for (int n = 0; n < 4; ++n)
                bfr[n] = *(const bf16x8*)(&Bs[wc + n * 16 + lr16][ks * 32 + lk8]);
#pragma unroll
            for (int m = 0; m < 4; ++m)
#pragma unroll
                for (int n = 0; n < 4; ++n)
                    acc[m][n] = MFMA16(af[m], bfr[n], acc[m][n]);
        }
    }

    // epilogue: C row=(lane>>4)*4+r (+16m+wr), col=lane&15 (+16n+wc); scatter to [B,H,T,64]
    const int r4 = (lane >> 4) << 2;
#pragma unroll
    for (int n = 0; n < 4; ++n) {
        const int ncol = nbase + wc + n * 16 + lr16;   // 0..1023 within this matrix
        const float bia = bias[ncol];
        const int h = ncol >> 6, d = ncol & 63;
#pragma unroll
        for (int m = 0; m < 4; ++m) {
#pragma unroll
            for (int r = 0; r < 4; ++r) {
                const int grow = bm * 128 + wr + m * 16 + r4 + r;  // 0..8191 = (b,t)
                const int b = grow >> 11, t = grow & 2047;
                outp[((size_t)(b * 16 + h) * 2048 + t) * 64 + d] = (bf16)(acc[m][n][r] + bia);
            }
        }
    }
}

// ---------------------------------------------------------------------------
// Kernel 2: V [B,H,T,64] -> V^T [B,H,64,T] via LDS 64x64 tile (coalesced both sides)
// ---------------------------------------------------------------------------
__global__ __launch_bounds__(256) void vtrans(const bf16* __restrict__ v, bf16* __restrict__ vt)
{
    __shared__ bf16 Ts[64][72];
    const int tid = threadIdx.x;
    const int bh  = blockIdx.y;
    const int t0  = blockIdx.x << 6;
#pragma unroll
    for (int i = 0; i < 2; ++i) {
        const int c   = tid + (i << 8);
        const int row = c >> 3;
        const int c8  = (c & 7) << 3;
        *(bf16x8*)(&Ts[row][c8]) = *(const bf16x8*)(v + ((size_t)bh * 2048 + t0 + row) * 64 + c8);
    }
    __syncthreads();
#pragma unroll
    for (int i = 0; i < 2; ++i) {
        const int c    = tid + (i << 8);
        const int drow = c >> 3;
        const int t8   = (c & 7) << 3;
        bf16x8 o;
#pragma unroll
        for (int j = 0; j < 8; ++j) o[j] = Ts[t8 + j][drow];
        *(bf16x8*)(vt + ((size_t)bh * 64 + drow) * 2048 + t0 + t8) = o;
    }
}

// ---------------------------------------------------------------------------
// Kernel 3: causal flash attention. grid(16 q-tiles, 64 bh), 4 independent waves
// per block (NO barriers: per-wave trip counts differ). Each wave: 32 q rows.
// KV tile = 64. Q in regs; K, V^T straight from global (L2-resident per head).
// Online softmax; P goes D-layout -> A-layout through per-wave LDS scratch.
// ---------------------------------------------------------------------------
__global__ __launch_bounds__(256) void attn_kernel(
    const bf16* __restrict__ q, const bf16* __restrict__ k,
    const bf16* __restrict__ vt, bf16* __restrict__ y)
{
    __shared__ bf16 Ps[4][32][72];   // per-wave P scratch, padded
    const int tid  = threadIdx.x;
    const int lane = tid & 63;
    const int wid  = tid >> 6;
    const int bh   = blockIdx.y;
    const int bb   = bh >> 4, hh = bh & 15;
    const int q0   = blockIdx.x * 128 + wid * 32;
    const bf16* __restrict__ qp  = q  + (size_t)bh * 2048 * 64;
    const bf16* __restrict__ kp  = k  + (size_t)bh * 2048 * 64;
    const bf16* __restrict__ vtp = vt + (size_t)bh * 64 * 2048;
    const int lr16 = lane & 15;
    const int lk8  = (lane >> 4) << 3;
    const int r4   = (lane >> 4) << 2;

    // Q fragments (A-operand): rows q0+mi*16+(lane&15), d = dk*32+(lane>>4)*8
    bf16x8 qf[2][2];
#pragma unroll
    for (int mi = 0; mi < 2; ++mi)
#pragma unroll
        for (int dk = 0; dk < 2; ++dk)
            qf[mi][dk] = *(const bf16x8*)(qp + (size_t)(q0 + mi * 16 + lr16) * 64 + dk * 32 + lk8);

    f32x4 of[2][4];
    float mS[2][4], lS[2][4];
#pragma unroll
    for (int mi = 0; mi < 2; ++mi)
#pragma unroll
        for (int j = 0; j < 4; ++j) {
            of[mi][j] = (f32x4){0.f, 0.f, 0.f, 0.f};
            mS[mi][j] = -1e30f;
            lS[mi][j] = 0.f;
        }

    const int ntiles = ((q0 + 31) >> 6) + 1;   // causal bound for this wave
    for (int tile = 0; tile < ntiles; ++tile) {
        const int kv0 = tile << 6;
        // ---- S = Q K^T ----
        f32x4 s[2][4];
#pragma unroll
        for (int mi = 0; mi < 2; ++mi)
#pragma unroll
            for (int kf = 0; kf < 4; ++kf)
                s[mi][kf] = (f32x4){0.f, 0.f, 0.f, 0.f};
#pragma unroll
        for (int kf = 0; kf < 4; ++kf) {
#pragma unroll
            for (int dk = 0; dk < 2; ++dk) {
                const bf16x8 kf8 = *(const bf16x8*)(kp + (size_t)(kv0 + kf * 16 + lr16) * 64 + dk * 32 + lk8);
                s[0][kf] = MFMA16(qf[0][dk], kf8, s[0][kf]);
                s[1][kf] = MFMA16(qf[1][dk], kf8, s[1][kf]);
            }
        }
        // ---- masked online softmax (rows spread over 16-lane groups) ----
        float pv[2][4][4];
#pragma unroll
        for (int mi = 0; mi < 2; ++mi) {
#pragma unroll
            for (int r = 0; r < 4; ++r) {
                const int qrow = q0 + mi * 16 + r4 + r;
                float sv[4];
                float rmax = -1e30f;
#pragma unroll
                for (int kf = 0; kf < 4; ++kf) {
                    const int kk = kv0 + kf * 16 + lr16;
                    float vv = s[mi][kf][r] * 0.125f;     // 1/sqrt(64)
                    vv = (kk <= qrow) ? vv : -1e30f;
                    sv[kf] = vv;
                    rmax = fmaxf(rmax, vv);
                }
                rmax = fmaxf(rmax, __shfl_xor(rmax, 1));
                rmax = fmaxf(rmax, __shfl_xor(rmax, 2));
                rmax = fmaxf(rmax, __shfl_xor(rmax, 4));
                rmax = fmaxf(rmax, __shfl_xor(rmax, 8));
                const float mold = mS[mi][r];
                const float mnew = fmaxf(mold, rmax);
                const float corr = __expf(mold - mnew);
                float rsum = 0.f;
#pragma unroll
                for (int kf = 0; kf < 4; ++kf) {
                    const float p = __expf(sv[kf] - mnew);
                    pv[mi][kf][r] = p;
                    rsum += p;
                }
                rsum += __shfl_xor(rsum, 1);
                rsum += __shfl_xor(rsum, 2);
                rsum += __shfl_xor(rsum, 4);
                rsum += __shfl_xor(rsum, 8);
                lS[mi][r] = lS[mi][r] * corr + rsum;
                mS[mi][r] = mnew;
#pragma unroll
                for (int nf = 0; nf < 4; ++nf) of[mi][nf][r] *= corr;
            }
        }
        // ---- P: D-layout -> A-layout via per-wave LDS ----
#pragma unroll
        for (int mi = 0; mi < 2; ++mi)
#pragma unroll
            for (int kf = 0; kf < 4; ++kf)
#pragma unroll
                for (int r = 0; r < 4; ++r)
                    Ps[wid][mi * 16 + r4 + r][kf * 16 + lr16] = (bf16)pv[mi][kf][r];
        asm volatile("s_waitcnt lgkmcnt(0)" ::: "memory");
        bf16x8 pa[2][2];
#pragma unroll
        for (int mi = 0; mi < 2; ++mi)
#pragma unroll
            for (int ks = 0; ks < 2; ++ks)
                pa[mi][ks] = *(const bf16x8*)(&Ps[wid][mi * 16 + lr16][ks * 32 + lk8]);
        // ---- O += P V  (V^T rows are contiguous in t) ----
#pragma unroll
        for (int nf = 0; nf < 4; ++nf) {
#pragma unroll
            for (int ks = 0; ks < 2; ++ks) {
                const bf16x8 vf = *(const bf16x8*)(vtp + (size_t)(nf * 16 + lr16) * 2048 + kv0 + ks * 32 + lk8);
                of[0][nf] = MFMA16(pa[0][ks], vf, of[0][nf]);
                of[1][nf] = MFMA16(pa[1][ks], vf, of[1][nf]);
            }
        }
    }
    // ---- epilogue: y[b][t][h*64+d] bf16 ----
#pragma unroll
    for (int mi = 0; mi < 2; ++mi) {
#pragma unroll
        for (int nf = 0; nf < 4; ++nf) {
#pragma unroll
            for (int r = 0; r < 4; ++r) {
                const float val = of[mi][nf][r] / lS[mi][r];
                const int qrow = q0 + mi * 16 + r4 + r;
                const int c = hh * 64 + nf * 16 + lr16;
                y[((size_t)(bb * 2048 + qrow)) * 1024 + c] = (bf16)val;
            }
        }
    }
}

// ---------------------------------------------------------------------------
// Kernel 4: output projection. A = y bf16 [8192][1024], B = Wp fp32, out fp32.
// ---------------------------------------------------------------------------
__global__ __launch_bounds__(256) void out_gemm(
    const bf16* __restrict__ y, const float* __restrict__ Wp,
    const float* __restrict__ bp, float* __restrict__ out)
{
    __shared__ bf16 As[128][72];
    __shared__ bf16 Bs[128][72];
    const int tid  = threadIdx.x;
    const int lane = tid & 63;
    const int wid  = tid >> 6;
    const int bm   = blockIdx.x;
    const int nbase = blockIdx.y << 7;
    const int wr   = (wid >> 1) << 6;
    const int wc   = (wid & 1) << 6;
    const int lr16 = lane & 15;
    const int lk8  = (lane >> 4) << 3;

    f32x4 acc[4][4];
#pragma unroll
    for (int m = 0; m < 4; ++m)
#pragma unroll
        for (int n = 0; n < 4; ++n)
            acc[m][n] = (f32x4){0.f, 0.f, 0.f, 0.f};

    for (int kt = 0; kt < 16; ++kt) {
        const int k0 = kt << 6;
        __syncthreads();
#pragma unroll
        for (int i = 0; i < 4; ++i) {        // A is already bf16: straight copy
            const int c   = tid + (i << 8);  // 0..1023 chunks of 8
            const int row = c >> 3;
            const int c8  = (c & 7) << 3;
            *(bf16x8*)(&As[row][c8]) = *(const bf16x8*)(y + (size_t)(bm * 128 + row) * 1024 + k0 + c8);
        }
#pragma unroll
        for (int i = 0; i < 8; ++i) {        // B: Wp fp32 -> bf16
            const int f   = tid + (i << 8);
            const int row = f >> 4;
            const int c4  = (f & 15) << 2;
            const float4 v = *(const float4*)(Wp + (size_t)(nbase + row) * 1024 + k0 + c4);
            bf16x4 pk = {(bf16)v.x, (bf16)v.y, (bf16)v.z, (bf16)v.w};
            *(bf16x4*)(&Bs[row][c4]) = pk;
        }
        __syncthreads();
#pragma unroll
        for (int ks = 0; ks < 2; ++ks) {
            bf16x8 af[4], bfr[4];
#pragma unroll
            for (int m = 0; m < 4; ++m)
                af[m] = *(const bf16x8*)(&As[wr + m * 16 + lr16][ks * 32 + lk8]);
#pragma unroll
            for (int n = 0; n < 4; ++n)
                bfr[n] = *(const bf16x8*)(&Bs[wc + n * 16 + lr16][ks * 32 + lk8]);
#pragma unroll
            for (int m = 0; m < 4; ++m)
#pragma unroll
                for (int n = 0; n < 4; ++n)
                    acc[m][n] = MFMA16(af[m], bfr[n], acc[m][n]);
        }
    }

    const int r4 = (lane >> 4) << 2;
#pragma unroll
    for (int n = 0; n < 4; ++n) {
        const int ncol = nbase + wc + n * 16 + lr16;
        const float bia = bp[ncol];
#pragma unroll
        for (int m = 0; m < 4; ++m) {
#pragma unroll
            for (int r = 0; r < 4; ++r) {
                const int grow = bm * 128 + wr + m * 16 + r4 + r;
                out[(size_t)grow * 1024 + ncol] = acc[m][n][r] + bia;
            }
        }
    }
}

// ---------------------------------------------------------------------------
extern "C" void kernel_launch(void* const* d_in, const int* in_sizes, int n_in,
                              void* d_out, int out_size, void* d_ws, size_t ws_size,
                              hipStream_t stream) {
    const float* x  = (const float*)d_in[0];
    const float* Wq = (const float*)d_in[1];
    const float* bq = (const float*)d_in[2];
    const float* Wk = (const float*)d_in[3];
    const float* bk = (const float*)d_in[4];
    const float* Wv = (const float*)d_in[5];
    const float* bv = (const float*)d_in[6];
    const float* Wp = (const float*)d_in[7];
    const float* bp = (const float*)d_in[8];
    float* out = (float*)d_out;

    char* ws = (char*)d_ws;
    const size_t MB16 = (size_t)16 * 1024 * 1024;
    bf16* qws  = (bf16*)(ws);
    bf16* kws  = (bf16*)(ws + MB16);
    bf16* vws  = (bf16*)(ws + 2 * MB16);
    bf16* vtws = (bf16*)(ws + 3 * MB16);
    bf16* yws  = vws;   // V's region is free after the transpose

    qkv_gemm<<<dim3(64, 24), 256, 0, stream>>>(x, Wq, Wk, Wv, bq, bk, bv, qws, kws, vws);
    vtrans<<<dim3(32, 64), 256, 0, stream>>>(vws, vtws);
    attn_kernel<<<dim3(16, 64), 256, 0, stream>>>(qws, kws, vtws, yws);
    out_gemm<<<dim3(64, 8), 256, 0, stream>>>(yws, Wp, bp, out);
}

// Round 3
// 515.050 us; speedup vs baseline: 1.2317x; 1.2317x over previous
//
#include <hip/hip_runtime.h>
#include <hip/hip_bf16.h>

// CausalSelfAttention: x@Wq^T,Wk^T,Wv^T -> heads -> causal flash attn -> @Wp^T + bp
// B=4 T=2048 C=1024 H=16 HD=64. All matmuls via mfma_f32_16x16x32_bf16 (fp32 accum).

using bf16   = __bf16;
using bf16x8 = __attribute__((ext_vector_type(8))) __bf16;
using bf16x4 = __attribute__((ext_vector_type(4))) __bf16;
using f32x4  = __attribute__((ext_vector_type(4))) float;

#define MFMA16(a, b, c) __builtin_amdgcn_mfma_f32_16x16x32_bf16((a), (b), (c), 0, 0, 0)

// ---------------------------------------------------------------------------
// Kernel 1: fused QKV projection GEMM.  M=8192 (b,t), N=3072 (3 x 1024), K=1024.
// ---------------------------------------------------------------------------
__global__ __launch_bounds__(256) void qkv_gemm(
    const float* __restrict__ x,
    const float* __restrict__ Wq, const float* __restrict__ Wk, const float* __restrict__ Wv,
    const float* __restrict__ bq, const float* __restrict__ bk, const float* __restrict__ bv,
    bf16* __restrict__ qws, bf16* __restrict__ kws, bf16* __restrict__ vws)
{
    __shared__ bf16 As[128][72];
    __shared__ bf16 Bs[128][72];
    const int tid  = threadIdx.x;
    const int lane = tid & 63;
    const int wid  = tid >> 6;
    const int bm   = blockIdx.x;
    const int bn   = blockIdx.y;
    const int widx  = bn >> 3;
    const int nbase = (bn & 7) << 7;
    const float* __restrict__ W    = (widx == 0) ? Wq : (widx == 1) ? Wk : Wv;
    const float* __restrict__ bias = (widx == 0) ? bq : (widx == 1) ? bk : bv;
    bf16* __restrict__ outp        = (widx == 0) ? qws : (widx == 1) ? kws : vws;

    const int wr   = (wid >> 1) << 6;
    const int wc   = (wid & 1) << 6;
    const int lr16 = lane & 15;
    const int lk8  = (lane >> 4) << 3;

    f32x4 acc[4][4];
#pragma unroll
    for (int m = 0; m < 4; ++m)
#pragma unroll
        for (int n = 0; n < 4; ++n)
            acc[m][n] = (f32x4){0.f, 0.f, 0.f, 0.f};

    for (int kt = 0; kt < 16; ++kt) {
        const int k0 = kt << 6;
        __syncthreads();
#pragma unroll
        for (int i = 0; i < 8; ++i) {
            const int f   = tid + (i << 8);
            const int row = f >> 4;
            const int c4  = (f & 15) << 2;
            const float4 v = *(const float4*)(x + (size_t)(bm * 128 + row) * 1024 + k0 + c4);
            bf16x4 pk = {(bf16)v.x, (bf16)v.y, (bf16)v.z, (bf16)v.w};
            *(bf16x4*)(&As[row][c4]) = pk;
        }
#pragma unroll
        for (int i = 0; i < 8; ++i) {
            const int f   = tid + (i << 8);
            const int row = f >> 4;
            const int c4  = (f & 15) << 2;
            const float4 v = *(const float4*)(W + (size_t)(nbase + row) * 1024 + k0 + c4);
            bf16x4 pk = {(bf16)v.x, (bf16)v.y, (bf16)v.z, (bf16)v.w};
            *(bf16x4*)(&Bs[row][c4]) = pk;
        }
        __syncthreads();
#pragma unroll
        for (int ks = 0; ks < 2; ++ks) {
            bf16x8 af[4], bfr[4];
#pragma unroll
            for (int m = 0; m < 4; ++m)
                af[m] = *(const bf16x8*)(&As[wr + m * 16 + lr16][ks * 32 + lk8]);
#pragma unroll
            for (int n = 0; n < 4; ++n)
                bfr[n] = *(const bf16x8*)(&Bs[wc + n * 16 + lr16][ks * 32 + lk8]);
#pragma unroll
            for (int m = 0; m < 4; ++m)
#pragma unroll
                for (int n = 0; n < 4; ++n)
                    acc[m][n] = MFMA16(af[m], bfr[n], acc[m][n]);
        }
    }

    const int r4 = (lane >> 4) << 2;
#pragma unroll
    for (int n = 0; n < 4; ++n) {
        const int ncol = nbase + wc + n * 16 + lr16;
        const float bia = bias[ncol];
        const int h = ncol >> 6, d = ncol & 63;
#pragma unroll
        for (int m = 0; m < 4; ++m) {
#pragma unroll
            for (int r = 0; r < 4; ++r) {
                const int grow = bm * 128 + wr + m * 16 + r4 + r;
                const int b = grow >> 11, t = grow & 2047;
                outp[((size_t)(b * 16 + h) * 2048 + t) * 64 + d] = (bf16)(acc[m][n][r] + bia);
            }
        }
    }
}

// ---------------------------------------------------------------------------
// Kernel 2: V [B,H,T,64] -> V^T [B,H,64,T]
// ---------------------------------------------------------------------------
__global__ __launch_bounds__(256) void vtrans(const bf16* __restrict__ v, bf16* __restrict__ vt)
{
    __shared__ bf16 Ts[64][72];
    const int tid = threadIdx.x;
    const int bh  = blockIdx.y;
    const int t0  = blockIdx.x << 6;
#pragma unroll
    for (int i = 0; i < 2; ++i) {
        const int c   = tid + (i << 8);
        const int row = c >> 3;
        const int c8  = (c & 7) << 3;
        *(bf16x8*)(&Ts[row][c8]) = *(const bf16x8*)(v + ((size_t)bh * 2048 + t0 + row) * 64 + c8);
    }
    __syncthreads();
#pragma unroll
    for (int i = 0; i < 2; ++i) {
        const int c    = tid + (i << 8);
        const int drow = c >> 3;
        const int t8   = (c & 7) << 3;
        bf16x8 o;
#pragma unroll
        for (int j = 0; j < 8; ++j) o[j] = Ts[t8 + j][drow];
        *(bf16x8*)(vt + ((size_t)bh * 64 + drow) * 2048 + t0 + t8) = o;
    }
}

// ---------------------------------------------------------------------------
// Kernel 3: causal flash attention, load-balanced.
// One wave per block. Wave-task = strip pair (s, 127-s), 16 q-rows per strip,
// so every wave does exactly ~33 KV tiles of 64 (zero imbalance). Q in regs
// (scale folded into exp2 constant), K register-prefetched one tile ahead,
// V issued before the P->LDS roundtrip. Mask only the diagonal tile. Per-lane
// partial l (no per-tile sum shuffles). Defer-max (THR=64 raw => exp arg <= 8).
// ---------------------------------------------------------------------------
__global__ __launch_bounds__(64, 4) void attn_kernel(
    const bf16* __restrict__ q, const bf16* __restrict__ k,
    const bf16* __restrict__ vt, bf16* __restrict__ y)
{
    __shared__ bf16 Ps[16][68];   // 68 elem rows: 4 row-groups hit distinct bank octets
    const int lane = threadIdx.x;
    const int p    = blockIdx.x;          // 0..63 pair index
    const int bh   = blockIdx.y;
    const int bb   = bh >> 4, hh = bh & 15;
    const bf16* __restrict__ qp  = q  + (size_t)bh * 2048 * 64;
    const bf16* __restrict__ kp  = k  + (size_t)bh * 2048 * 64;
    const bf16* __restrict__ vtp = vt + (size_t)bh * 64 * 2048;
    const int lr16 = lane & 15;
    const int lk8  = (lane >> 4) << 3;
    const int r4   = (lane >> 4) << 2;
    const float SCL = 0.18033688f;        // (1/sqrt(64)) * log2(e)

    for (int half = 0; half < 2; ++half) {
        const int s  = half ? (127 - p) : p;
        const int q0 = s << 4;
        const int td = q0 >> 6;           // diagonal tile index; tiles 0..td-1 are full

        bf16x8 qf[2];
#pragma unroll
        for (int dk = 0; dk < 2; ++dk)
            qf[dk] = *(const bf16x8*)(qp + (size_t)(q0 + lr16) * 64 + dk * 32 + lk8);

        f32x4 of[4];
        float mS[4], lp[4];
#pragma unroll
        for (int nf = 0; nf < 4; ++nf) of[nf] = (f32x4){0.f, 0.f, 0.f, 0.f};
#pragma unroll
        for (int r = 0; r < 4; ++r) { mS[r] = -1e30f; lp[r] = 0.f; }

        // K prologue: tile 0
        bf16x8 kr[4][2];
#pragma unroll
        for (int kf = 0; kf < 4; ++kf)
#pragma unroll
            for (int dk = 0; dk < 2; ++dk)
                kr[kf][dk] = *(const bf16x8*)(kp + (size_t)(kf * 16 + lr16) * 64 + dk * 32 + lk8);

        for (int t = 0; t <= td; ++t) {
            const int kv0 = t << 6;
            // ---- S = Q K^T (K from prefetch regs) ----
            f32x4 sv[4];
#pragma unroll
            for (int kf = 0; kf < 4; ++kf) {
                sv[kf] = (f32x4){0.f, 0.f, 0.f, 0.f};
                sv[kf] = MFMA16(qf[0], kr[kf][0], sv[kf]);
                sv[kf] = MFMA16(qf[1], kr[kf][1], sv[kf]);
            }
            // ---- prefetch K(t+1); flies under softmax + P + PV ----
            if (t < td) {
                const bf16* kpn = kp + (size_t)(kv0 + 64) * 64;
#pragma unroll
                for (int kf = 0; kf < 4; ++kf)
#pragma unroll
                    for (int dk = 0; dk < 2; ++dk)
                        kr[kf][dk] = *(const bf16x8*)(kpn + (size_t)(kf * 16 + lr16) * 64 + dk * 32 + lk8);
            }
            // ---- mask: diagonal tile only ----
            if (t == td) {
#pragma unroll
                for (int kf = 0; kf < 4; ++kf) {
                    const int kk = kv0 + kf * 16 + lr16;
#pragma unroll
                    for (int r = 0; r < 4; ++r) {
                        const int qrow = q0 + r4 + r;
                        if (kk > qrow) sv[kf][r] = -3.0e38f;
                    }
                }
            }
            // ---- row max (16-lane groups; 4 row-slots in parallel per shuffle) ----
            float gmax[4];
#pragma unroll
            for (int r = 0; r < 4; ++r) {
                float g = fmaxf(fmaxf(sv[0][r], sv[1][r]), fmaxf(sv[2][r], sv[3][r]));
                g = fmaxf(g, __shfl_xor(g, 1));
                g = fmaxf(g, __shfl_xor(g, 2));
                g = fmaxf(g, __shfl_xor(g, 4));
                g = fmaxf(g, __shfl_xor(g, 8));
                gmax[r] = g;
            }
            // ---- defer-max: rescale only when some row grew past THR ----
            bool needre = false;
#pragma unroll
            for (int r = 0; r < 4; ++r) needre |= (gmax[r] > mS[r] + 64.0f);
            if (__ballot(needre) != 0ull) {
#pragma unroll
                for (int r = 0; r < 4; ++r) {
                    const float mn   = fmaxf(mS[r], gmax[r]);
                    const float corr = exp2f((mS[r] - mn) * SCL);
                    mS[r] = mn;
                    lp[r] *= corr;
#pragma unroll
                    for (int nf = 0; nf < 4; ++nf) of[nf][r] *= corr;
                }
            }
            // ---- P = exp2((S - m)*SCL); per-lane partial l ----
#pragma unroll
            for (int kf = 0; kf < 4; ++kf)
#pragma unroll
                for (int r = 0; r < 4; ++r)
                    sv[kf][r] = exp2f((sv[kf][r] - mS[r]) * SCL);
#pragma unroll
            for (int r = 0; r < 4; ++r)
                lp[r] += sv[0][r] + sv[1][r] + sv[2][r] + sv[3][r];
            // ---- V loads: issue before LDS roundtrip so latency overlaps ----
            bf16x8 vf[4][2];
#pragma unroll
            for (int nf = 0; nf < 4; ++nf)
#pragma unroll
                for (int ks = 0; ks < 2; ++ks)
                    vf[nf][ks] = *(const bf16x8*)(vtp + (size_t)(nf * 16 + lr16) * 2048 + kv0 + ks * 32 + lk8);
            // ---- P: D-layout -> A-layout via LDS ----
#pragma unroll
            for (int kf = 0; kf < 4; ++kf)
#pragma unroll
                for (int r = 0; r < 4; ++r)
                    Ps[r4 + r][kf * 16 + lr16] = (bf16)sv[kf][r];
            asm volatile("s_waitcnt lgkmcnt(0)" ::: "memory");
            __builtin_amdgcn_sched_barrier(0);
            bf16x8 pa[2];
#pragma unroll
            for (int ks = 0; ks < 2; ++ks)
                pa[ks] = *(const bf16x8*)(&Ps[lr16][ks * 32 + lk8]);
            // ---- O += P V ----
#pragma unroll
            for (int nf = 0; nf < 4; ++nf) {
                of[nf] = MFMA16(pa[0], vf[nf][0], of[nf]);
                of[nf] = MFMA16(pa[1], vf[nf][1], of[nf]);
            }
        }

        // ---- epilogue: reduce per-lane l partials once, normalize, store ----
#pragma unroll
        for (int r = 0; r < 4; ++r) {
            float l = lp[r];
            l += __shfl_xor(l, 1);
            l += __shfl_xor(l, 2);
            l += __shfl_xor(l, 4);
            l += __shfl_xor(l, 8);
            lp[r] = 1.0f / l;
        }
#pragma unroll
        for (int nf = 0; nf < 4; ++nf)
#pragma unroll
            for (int r = 0; r < 4; ++r)
                y[((size_t)(bb * 2048 + q0 + r4 + r)) * 1024 + hh * 64 + nf * 16 + lr16] =
                    (bf16)(of[nf][r] * lp[r]);
    }
}

// ---------------------------------------------------------------------------
// Kernel 4: output projection. A = y bf16 [8192][1024], B = Wp fp32, out fp32.
// ---------------------------------------------------------------------------
__global__ __launch_bounds__(256) void out_gemm(
    const bf16* __restrict__ y, const float* __restrict__ Wp,
    const float* __restrict__ bp, float* __restrict__ out)
{
    __shared__ bf16 As[128][72];
    __shared__ bf16 Bs[128][72];
    const int tid  = threadIdx.x;
    const int lane = tid & 63;
    const int wid  = tid >> 6;
    const int bm   = blockIdx.x;
    const int nbase = blockIdx.y << 7;
    const int wr   = (wid >> 1) << 6;
    const int wc   = (wid & 1) << 6;
    const int lr16 = lane & 15;
    const int lk8  = (lane >> 4) << 3;

    f32x4 acc[4][4];
#pragma unroll
    for (int m = 0; m < 4; ++m)
#pragma unroll
        for (int n = 0; n < 4; ++n)
            acc[m][n] = (f32x4){0.f, 0.f, 0.f, 0.f};

    for (int kt = 0; kt < 16; ++kt) {
        const int k0 = kt << 6;
        __syncthreads();
#pragma unroll
        for (int i = 0; i < 4; ++i) {
            const int c   = tid + (i << 8);
            const int row = c >> 3;
            const int c8  = (c & 7) << 3;
            *(bf16x8*)(&As[row][c8]) = *(const bf16x8*)(y + (size_t)(bm * 128 + row) * 1024 + k0 + c8);
        }
#pragma unroll
        for (int i = 0; i < 8; ++i) {
            const int f   = tid + (i << 8);
            const int row = f >> 4;
            const int c4  = (f & 15) << 2;
            const float4 v = *(const float4*)(Wp + (size_t)(nbase + row) * 1024 + k0 + c4);
            bf16x4 pk = {(bf16)v.x, (bf16)v.y, (bf16)v.z, (bf16)v.w};
            *(bf16x4*)(&Bs[row][c4]) = pk;
        }
        __syncthreads();
#pragma unroll
        for (int ks = 0; ks < 2; ++ks) {
            bf16x8 af[4], bfr[4];
#pragma unroll
            for (int m = 0; m < 4; ++m)
                af[m] = *(const bf16x8*)(&As[wr + m * 16 + lr16][ks * 32 + lk8]);
#pragma unroll
            for (int n = 0; n < 4; ++n)
                bfr[n] = *(const bf16x8*)(&Bs[wc + n * 16 + lr16][ks * 32 + lk8]);
#pragma unroll
            for (int m = 0; m < 4; ++m)
#pragma unroll
                for (int n = 0; n < 4; ++n)
                    acc[m][n] = MFMA16(af[m], bfr[n], acc[m][n]);
        }
    }

    const int r4 = (lane >> 4) << 2;
#pragma unroll
    for (int n = 0; n < 4; ++n) {
        const int ncol = nbase + wc + n * 16 + lr16;
        const float bia = bp[ncol];
#pragma unroll
        for (int m = 0; m < 4; ++m) {
#pragma unroll
            for (int r = 0; r < 4; ++r) {
                const int grow = bm * 128 + wr + m * 16 + r4 + r;
                out[(size_t)grow * 1024 + ncol] = acc[m][n][r] + bia;
            }
        }
    }
}

// ---------------------------------------------------------------------------
extern "C" void kernel_launch(void* const* d_in, const int* in_sizes, int n_in,
                              void* d_out, int out_size, void* d_ws, size_t ws_size,
                              hipStream_t stream) {
    const float* x  = (const float*)d_in[0];
    const float* Wq = (const float*)d_in[1];
    const float* bq = (const float*)d_in[2];
    const float* Wk = (const float*)d_in[3];
    const float* bk = (const float*)d_in[4];
    const float* Wv = (const float*)d_in[5];
    const float* bv = (const float*)d_in[6];
    const float* Wp = (const float*)d_in[7];
    const float* bp = (const float*)d_in[8];
    float* out = (float*)d_out;

    char* ws = (char*)d_ws;
    const size_t MB16 = (size_t)16 * 1024 * 1024;
    bf16* qws  = (bf16*)(ws);
    bf16* kws  = (bf16*)(ws + MB16);
    bf16* vws  = (bf16*)(ws + 2 * MB16);
    bf16* vtws = (bf16*)(ws + 3 * MB16);
    bf16* yws  = vws;   // V's region is free after the transpose

    qkv_gemm<<<dim3(64, 24), 256, 0, stream>>>(x, Wq, Wk, Wv, bq, bk, bv, qws, kws, vws);
    vtrans<<<dim3(32, 64), 256, 0, stream>>>(vws, vtws);
    attn_kernel<<<dim3(64, 64), 64, 0, stream>>>(qws, kws, vtws, yws);
    out_gemm<<<dim3(64, 8), 256, 0, stream>>>(yws, Wp, bp, out);
}

// Round 5
// 333.695 us; speedup vs baseline: 1.9011x; 1.5435x over previous
//
#include <hip/hip_runtime.h>
#include <hip/hip_bf16.h>

// CausalSelfAttention: x@Wq^T,Wk^T,Wv^T -> heads -> causal flash attn -> @Wp^T + bp
// B=4 T=2048 C=1024 H=16 HD=64. All matmuls via mfma_f32_16x16x32_bf16 (fp32 accum).

using bf16   = __bf16;
using bf16x8 = __attribute__((ext_vector_type(8))) __bf16;
using bf16x4 = __attribute__((ext_vector_type(4))) __bf16;
using f32x4  = __attribute__((ext_vector_type(4))) float;

#define MFMA16(a, b, c) __builtin_amdgcn_mfma_f32_16x16x32_bf16((a), (b), (c), 0, 0, 0)

// ---------------------------------------------------------------------------
// Kernel 1: fused QKV projection GEMM.  M=8192 (b,t), N=3072 (3 x 1024), K=1024.
// ---------------------------------------------------------------------------
__global__ __launch_bounds__(256) void qkv_gemm(
    const float* __restrict__ x,
    const float* __restrict__ Wq, const float* __restrict__ Wk, const float* __restrict__ Wv,
    const float* __restrict__ bq, const float* __restrict__ bk, const float* __restrict__ bv,
    bf16* __restrict__ qws, bf16* __restrict__ kws, bf16* __restrict__ vws)
{
    __shared__ bf16 As[128][72];
    __shared__ bf16 Bs[128][72];
    const int tid  = threadIdx.x;
    const int lane = tid & 63;
    const int wid  = tid >> 6;
    const int bm   = blockIdx.x;
    const int bn   = blockIdx.y;
    const int widx  = bn >> 3;
    const int nbase = (bn & 7) << 7;
    const float* __restrict__ W    = (widx == 0) ? Wq : (widx == 1) ? Wk : Wv;
    const float* __restrict__ bias = (widx == 0) ? bq : (widx == 1) ? bk : bv;
    bf16* __restrict__ outp        = (widx == 0) ? qws : (widx == 1) ? kws : vws;

    const int wr   = (wid >> 1) << 6;
    const int wc   = (wid & 1) << 6;
    const int lr16 = lane & 15;
    const int lk8  = (lane >> 4) << 3;

    f32x4 acc[4][4];
#pragma unroll
    for (int m = 0; m < 4; ++m)
#pragma unroll
        for (int n = 0; n < 4; ++n)
            acc[m][n] = (f32x4){0.f, 0.f, 0.f, 0.f};

    for (int kt = 0; kt < 16; ++kt) {
        const int k0 = kt << 6;
        __syncthreads();
#pragma unroll
        for (int i = 0; i < 8; ++i) {
            const int f   = tid + (i << 8);
            const int row = f >> 4;
            const int c4  = (f & 15) << 2;
            const float4 v = *(const float4*)(x + (size_t)(bm * 128 + row) * 1024 + k0 + c4);
            bf16x4 pk = {(bf16)v.x, (bf16)v.y, (bf16)v.z, (bf16)v.w};
            *(bf16x4*)(&As[row][c4]) = pk;
        }
#pragma unroll
        for (int i = 0; i < 8; ++i) {
            const int f   = tid + (i << 8);
            const int row = f >> 4;
            const int c4  = (f & 15) << 2;
            const float4 v = *(const float4*)(W + (size_t)(nbase + row) * 1024 + k0 + c4);
            bf16x4 pk = {(bf16)v.x, (bf16)v.y, (bf16)v.z, (bf16)v.w};
            *(bf16x4*)(&Bs[row][c4]) = pk;
        }
        __syncthreads();
#pragma unroll
        for (int ks = 0; ks < 2; ++ks) {
            bf16x8 af[4], bfr[4];
#pragma unroll
            for (int m = 0; m < 4; ++m)
                af[m] = *(const bf16x8*)(&As[wr + m * 16 + lr16][ks * 32 + lk8]);
#pragma unroll
            for (int n = 0; n < 4; ++n)
                bfr[n] = *(const bf16x8*)(&Bs[wc + n * 16 + lr16][ks * 32 + lk8]);
#pragma unroll
            for (int m = 0; m < 4; ++m)
#pragma unroll
                for (int n = 0; n < 4; ++n)
                    acc[m][n] = MFMA16(af[m], bfr[n], acc[m][n]);
        }
    }

    const int r4 = (lane >> 4) << 2;
#pragma unroll
    for (int n = 0; n < 4; ++n) {
        const int ncol = nbase + wc + n * 16 + lr16;
        const float bia = bias[ncol];
        const int h = ncol >> 6, d = ncol & 63;
#pragma unroll
        for (int m = 0; m < 4; ++m) {
#pragma unroll
            for (int r = 0; r < 4; ++r) {
                const int grow = bm * 128 + wr + m * 16 + r4 + r;
                const int b = grow >> 11, t = grow & 2047;
                outp[((size_t)(b * 16 + h) * 2048 + t) * 64 + d] = (bf16)(acc[m][n][r] + bia);
            }
        }
    }
}

// ---------------------------------------------------------------------------
// Kernel 2: V [B,H,T,64] -> V^T [B,H,64,T]
// ---------------------------------------------------------------------------
__global__ __launch_bounds__(256) void vtrans(const bf16* __restrict__ v, bf16* __restrict__ vt)
{
    __shared__ bf16 Ts[64][72];
    const int tid = threadIdx.x;
    const int bh  = blockIdx.y;
    const int t0  = blockIdx.x << 6;
#pragma unroll
    for (int i = 0; i < 2; ++i) {
        const int c   = tid + (i << 8);
        const int row = c >> 3;
        const int c8  = (c & 7) << 3;
        *(bf16x8*)(&Ts[row][c8]) = *(const bf16x8*)(v + ((size_t)bh * 2048 + t0 + row) * 64 + c8);
    }
    __syncthreads();
#pragma unroll
    for (int i = 0; i < 2; ++i) {
        const int c    = tid + (i << 8);
        const int drow = c >> 3;
        const int t8   = (c & 7) << 3;
        bf16x8 o;
#pragma unroll
        for (int j = 0; j < 8; ++j) o[j] = Ts[t8 + j][drow];
        *(bf16x8*)(vt + ((size_t)bh * 64 + drow) * 2048 + t0 + t8) = o;
    }
}

// ---------------------------------------------------------------------------
// Kernel 3: causal flash attention, block-shared KV in LDS.
// 512 blocks x 256 threads. Block-task = q-block pair (s, 15-s), 128 rows each
// -> exactly 34 KV tiles per block (perfect balance). 4 waves x 32 q-rows.
// K and V^T tiles (64x64) staged once per block into padded LDS, double-
// buffered, ONE barrier per tile (stage-write to buf^1 after compute; top-of-
// loop sync publishes). XCD-aware mapping: each XCD owns 8 heads entirely, so
// a head's 512 KB K/V stays in its 4 MB L2. Softmax: diagonal-frag-only mask,
// defer-max, per-lane partial l; fully-masked frags fall out via exp2(-inf)=0.
// ---------------------------------------------------------------------------
__global__ __launch_bounds__(256, 2) void attn_kernel(
    const bf16* __restrict__ q, const bf16* __restrict__ k,
    const bf16* __restrict__ vt, bf16* __restrict__ y)
{
    __shared__ bf16 Ks[2][64][72];
    __shared__ bf16 Vs[2][64][72];
    __shared__ bf16 Ps[4][32][72];
    const int tid  = threadIdx.x;
    const int lane = tid & 63;
    const int wid  = tid >> 6;
    // XCD-aware task mapping: lin%8 = XCD; each XCD gets heads {x, x+8, .., x+56}
    const int lin  = blockIdx.x;
    const int xcd  = lin & 7;
    const int jj   = lin >> 3;                 // 0..63
    const int bh   = xcd + ((jj >> 3) << 3);   // 8 heads per XCD
    const int pr   = jj & 7;                   // pair index 0..7
    const int bb   = bh >> 4, hh = bh & 15;
    const bf16* __restrict__ qp  = q  + (size_t)bh * 2048 * 64;
    const bf16* __restrict__ kp  = k  + (size_t)bh * 2048 * 64;
    const bf16* __restrict__ vtp = vt + (size_t)bh * 64 * 2048;
    const int lr16 = lane & 15;
    const int lk8  = (lane >> 4) << 3;
    const int r4   = (lane >> 4) << 2;
    const float SCL = 0.18033688f;             // (1/sqrt(64)) * log2(e)
    // staging geometry: 64x64 bf16 tile = 512 chunks of 8; thread owns 2 chunks
    const int srow = tid >> 3;                 // 0..31
    const int scol = (tid & 7) << 3;           // 0,8,..,56

    for (int half = 0; half < 2; ++half) {
        const int s    = half ? (15 - pr) : pr;
        const int q0   = s << 7;
        const int nt   = 2 * s + 2;            // tiles 0..2s+1
        const int wrow = q0 + wid * 32;        // this wave's first q row

        bf16x8 qf[2][2];
#pragma unroll
        for (int mi = 0; mi < 2; ++mi)
#pragma unroll
            for (int dk = 0; dk < 2; ++dk)
                qf[mi][dk] = *(const bf16x8*)(qp + (size_t)(wrow + mi * 16 + lr16) * 64 + dk * 32 + lk8);

        f32x4 of[2][4];
        float mS[2][4], lp[2][4];
#pragma unroll
        for (int mi = 0; mi < 2; ++mi)
#pragma unroll
            for (int nf = 0; nf < 4; ++nf) of[mi][nf] = (f32x4){0.f, 0.f, 0.f, 0.f};
#pragma unroll
        for (int mi = 0; mi < 2; ++mi)
#pragma unroll
            for (int r = 0; r < 4; ++r) { mS[mi][r] = -1e30f; lp[mi][r] = 0.f; }

        // ---- prologue: stage tile 0 into buf 0 ----
        {
            bf16x8 ka = *(const bf16x8*)(kp + (size_t)srow * 64 + scol);
            bf16x8 kb = *(const bf16x8*)(kp + (size_t)(srow + 32) * 64 + scol);
            bf16x8 va = *(const bf16x8*)(vtp + (size_t)srow * 2048 + scol);
            bf16x8 vb = *(const bf16x8*)(vtp + (size_t)(srow + 32) * 2048 + scol);
            *(bf16x8*)(&Ks[0][srow][scol])      = ka;
            *(bf16x8*)(&Ks[0][srow + 32][scol]) = kb;
            *(bf16x8*)(&Vs[0][srow][scol])      = va;
            *(bf16x8*)(&Vs[0][srow + 32][scol]) = vb;
        }
        int cur = 0;

        for (int t = 0; t < nt; ++t) {
            const int kv0 = t << 6;
            __syncthreads();                   // buf[cur] published
            // ---- issue next-tile global loads; latency hides under compute ----
            bf16x8 ka, kb, va, vb;
            const bool pf = (t + 1 < nt);
            if (pf) {
                const int kn = kv0 + 64;
                ka = *(const bf16x8*)(kp + (size_t)(kn + srow) * 64 + scol);
                kb = *(const bf16x8*)(kp + (size_t)(kn + srow + 32) * 64 + scol);
                va = *(const bf16x8*)(vtp + (size_t)srow * 2048 + kn + scol);
                vb = *(const bf16x8*)(vtp + (size_t)(srow + 32) * 2048 + kn + scol);
            }
            // ---- S = Q K^T from LDS ----
            f32x4 sv[2][4];
#pragma unroll
            for (int mi = 0; mi < 2; ++mi)
#pragma unroll
                for (int kf = 0; kf < 4; ++kf)
                    sv[mi][kf] = (f32x4){0.f, 0.f, 0.f, 0.f};
#pragma unroll
            for (int kf = 0; kf < 4; ++kf) {
                const bf16x8 k0 = *(const bf16x8*)(&Ks[cur][kf * 16 + lr16][lk8]);
                const bf16x8 k1 = *(const bf16x8*)(&Ks[cur][kf * 16 + lr16][32 + lk8]);
                sv[0][kf] = MFMA16(qf[0][0], k0, sv[0][kf]);
                sv[0][kf] = MFMA16(qf[0][1], k1, sv[0][kf]);
                sv[1][kf] = MFMA16(qf[1][0], k0, sv[1][kf]);
                sv[1][kf] = MFMA16(qf[1][1], k1, sv[1][kf]);
            }
            // ---- causal mask (only frags the diagonal can touch) ----
#pragma unroll
            for (int mi = 0; mi < 2; ++mi) {
                const int rb = wrow + mi * 16;
                if (kv0 + 63 > rb) {
#pragma unroll
                    for (int kf = 0; kf < 4; ++kf) {
                        const int kk = kv0 + kf * 16 + lr16;
#pragma unroll
                        for (int r = 0; r < 4; ++r)
                            if (kk > rb + r4 + r) sv[mi][kf][r] = -3.0e38f;
                    }
                }
            }
            // ---- row max ----
            float gmax[2][4];
#pragma unroll
            for (int mi = 0; mi < 2; ++mi)
#pragma unroll
                for (int r = 0; r < 4; ++r) {
                    float g = fmaxf(fmaxf(sv[mi][0][r], sv[mi][1][r]),
                                    fmaxf(sv[mi][2][r], sv[mi][3][r]));
                    g = fmaxf(g, __shfl_xor(g, 1));
                    g = fmaxf(g, __shfl_xor(g, 2));
                    g = fmaxf(g, __shfl_xor(g, 4));
                    g = fmaxf(g, __shfl_xor(g, 8));
                    gmax[mi][r] = g;
                }
            // ---- defer-max rescale ----
            bool needre = false;
#pragma unroll
            for (int mi = 0; mi < 2; ++mi)
#pragma unroll
                for (int r = 0; r < 4; ++r) needre |= (gmax[mi][r] > mS[mi][r] + 64.0f);
            if (__ballot(needre) != 0ull) {
#pragma unroll
                for (int mi = 0; mi < 2; ++mi)
#pragma unroll
                    for (int r = 0; r < 4; ++r) {
                        const float mn   = fmaxf(mS[mi][r], gmax[mi][r]);
                        const float corr = exp2f((mS[mi][r] - mn) * SCL);
                        mS[mi][r] = mn;
                        lp[mi][r] *= corr;
#pragma unroll
                        for (int nf = 0; nf < 4; ++nf) of[mi][nf][r] *= corr;
                    }
            }
            // ---- P = exp2((S-m)*SCL); per-lane partial l ----
#pragma unroll
            for (int mi = 0; mi < 2; ++mi) {
#pragma unroll
                for (int kf = 0; kf < 4; ++kf)
#pragma unroll
                    for (int r = 0; r < 4; ++r)
                        sv[mi][kf][r] = exp2f((sv[mi][kf][r] - mS[mi][r]) * SCL);
#pragma unroll
                for (int r = 0; r < 4; ++r)
                    lp[mi][r] += sv[mi][0][r] + sv[mi][1][r] + sv[mi][2][r] + sv[mi][3][r];
            }
            // ---- P: D-layout -> A-layout via per-wave LDS ----
#pragma unroll
            for (int mi = 0; mi < 2; ++mi)
#pragma unroll
                for (int kf = 0; kf < 4; ++kf)
#pragma unroll
                    for (int r = 0; r < 4; ++r)
                        Ps[wid][mi * 16 + r4 + r][kf * 16 + lr16] = (bf16)sv[mi][kf][r];
            asm volatile("s_waitcnt lgkmcnt(0)" ::: "memory");
            __builtin_amdgcn_sched_barrier(0);
            bf16x8 pa[2][2];
#pragma unroll
            for (int mi = 0; mi < 2; ++mi)
#pragma unroll
                for (int ks = 0; ks < 2; ++ks)
                    pa[mi][ks] = *(const bf16x8*)(&Ps[wid][mi * 16 + lr16][ks * 32 + lk8]);
            // ---- O += P V from LDS ----
#pragma unroll
            for (int nf = 0; nf < 4; ++nf) {
                const bf16x8 v0 = *(const bf16x8*)(&Vs[cur][nf * 16 + lr16][lk8]);
                const bf16x8 v1 = *(const bf16x8*)(&Vs[cur][nf * 16 + lr16][32 + lk8]);
                of[0][nf] = MFMA16(pa[0][0], v0, of[0][nf]);
                of[0][nf] = MFMA16(pa[0][1], v1, of[0][nf]);
                of[1][nf] = MFMA16(pa[1][0], v0, of[1][nf]);
                of[1][nf] = MFMA16(pa[1][1], v1, of[1][nf]);
            }
            // ---- write next tile into the other buffer ----
            if (pf) {
                *(bf16x8*)(&Ks[cur ^ 1][srow][scol])      = ka;
                *(bf16x8*)(&Ks[cur ^ 1][srow + 32][scol]) = kb;
                *(bf16x8*)(&Vs[cur ^ 1][srow][scol])      = va;
                *(bf16x8*)(&Vs[cur ^ 1][srow + 32][scol]) = vb;
            }
            cur ^= 1;
        }

        // ---- epilogue: reduce l, normalize, store ----
#pragma unroll
        for (int mi = 0; mi < 2; ++mi)
#pragma unroll
            for (int r = 0; r < 4; ++r) {
                float l = lp[mi][r];
                l += __shfl_xor(l, 1);
                l += __shfl_xor(l, 2);
                l += __shfl_xor(l, 4);
                l += __shfl_xor(l, 8);
                lp[mi][r] = 1.0f / l;
            }
#pragma unroll
        for (int mi = 0; mi < 2; ++mi)
#pragma unroll
            for (int nf = 0; nf < 4; ++nf)
#pragma unroll
                for (int r = 0; r < 4; ++r)
                    y[((size_t)(bb * 2048 + wrow + mi * 16 + r4 + r)) * 1024 + hh * 64 + nf * 16 + lr16] =
                        (bf16)(of[mi][nf][r] * lp[mi][r]);
    }
}

// ---------------------------------------------------------------------------
// Kernel 4: output projection. A = y bf16 [8192][1024], B = Wp fp32, out fp32.
// ---------------------------------------------------------------------------
__global__ __launch_bounds__(256) void out_gemm(
    const bf16* __restrict__ y, const float* __restrict__ Wp,
    const float* __restrict__ bp, float* __restrict__ out)
{
    __shared__ bf16 As[128][72];
    __shared__ bf16 Bs[128][72];
    const int tid  = threadIdx.x;
    const int lane = tid & 63;
    const int wid  = tid >> 6;
    const int bm   = blockIdx.x;
    const int nbase = blockIdx.y << 7;
    const int wr   = (wid >> 1) << 6;
    const int wc   = (wid & 1) << 6;
    const int lr16 = lane & 15;
    const int lk8  = (lane >> 4) << 3;

    f32x4 acc[4][4];
#pragma unroll
    for (int m = 0; m < 4; ++m)
#pragma unroll
        for (int n = 0; n < 4; ++n)
            acc[m][n] = (f32x4){0.f, 0.f, 0.f, 0.f};

    for (int kt = 0; kt < 16; ++kt) {
        const int k0 = kt << 6;
        __syncthreads();
#pragma unroll
        for (int i = 0; i < 4; ++i) {
            const int c   = tid + (i << 8);
            const int row = c >> 3;
            const int c8  = (c & 7) << 3;
            *(bf16x8*)(&As[row][c8]) = *(const bf16x8*)(y + (size_t)(bm * 128 + row) * 1024 + k0 + c8);
        }
#pragma unroll
        for (int i = 0; i < 8; ++i) {
            const int f   = tid + (i << 8);
            const int row = f >> 4;
            const int c4  = (f & 15) << 2;
            const float4 v = *(const float4*)(Wp + (size_t)(nbase + row) * 1024 + k0 + c4);
            bf16x4 pk = {(bf16)v.x, (bf16)v.y, (bf16)v.z, (bf16)v.w};
            *(bf16x4*)(&Bs[row][c4]) = pk;
        }
        __syncthreads();
#pragma unroll
        for (int ks = 0; ks < 2; ++ks) {
            bf16x8 af[4], bfr[4];
#pragma unroll
            for (int m = 0; m < 4; ++m)
                af[m] = *(const bf16x8*)(&As[wr + m * 16 + lr16][ks * 32 + lk8]);
#pragma unroll
            for (int n = 0; n < 4; ++n)
                bfr[n] = *(const bf16x8*)(&Bs[wc + n * 16 + lr16][ks * 32 + lk8]);
#pragma unroll
            for (int m = 0; m < 4; ++m)
#pragma unroll
                for (int n = 0; n < 4; ++n)
                    acc[m][n] = MFMA16(af[m], bfr[n], acc[m][n]);
        }
    }

    const int r4 = (lane >> 4) << 2;
#pragma unroll
    for (int n = 0; n < 4; ++n) {
        const int ncol = nbase + wc + n * 16 + lr16;
        const float bia = bp[ncol];
#pragma unroll
        for (int m = 0; m < 4; ++m) {
#pragma unroll
            for (int r = 0; r < 4; ++r) {
                const int grow = bm * 128 + wr + m * 16 + r4 + r;
                out[(size_t)grow * 1024 + ncol] = acc[m][n][r] + bia;
            }
        }
    }
}

// ---------------------------------------------------------------------------
extern "C" void kernel_launch(void* const* d_in, const int* in_sizes, int n_in,
                              void* d_out, int out_size, void* d_ws, size_t ws_size,
                              hipStream_t stream) {
    const float* x  = (const float*)d_in[0];
    const float* Wq = (const float*)d_in[1];
    const float* bq = (const float*)d_in[2];
    const float* Wk = (const float*)d_in[3];
    const float* bk = (const float*)d_in[4];
    const float* Wv = (const float*)d_in[5];
    const float* bv = (const float*)d_in[6];
    const float* Wp = (const float*)d_in[7];
    const float* bp = (const float*)d_in[8];
    float* out = (float*)d_out;

    char* ws = (char*)d_ws;
    const size_t MB16 = (size_t)16 * 1024 * 1024;
    bf16* qws  = (bf16*)(ws);
    bf16* kws  = (bf16*)(ws + MB16);
    bf16* vws  = (bf16*)(ws + 2 * MB16);
    bf16* vtws = (bf16*)(ws + 3 * MB16);
    bf16* yws  = vws;   // V's region is free after the transpose

    qkv_gemm<<<dim3(64, 24), 256, 0, stream>>>(x, Wq, Wk, Wv, bq, bk, bv, qws, kws, vws);
    vtrans<<<dim3(32, 64), 256, 0, stream>>>(vws, vtws);
    attn_kernel<<<512, 256, 0, stream>>>(qws, kws, vtws, yws);
    out_gemm<<<dim3(64, 8), 256, 0, stream>>>(yws, Wp, bp, out);
}

// Round 10
// 291.934 us; speedup vs baseline: 2.1730x; 1.1430x over previous
//
#include <hip/hip_runtime.h>
#include <hip/hip_bf16.h>

// CausalSelfAttention: x@Wq^T,Wk^T,Wv^T -> heads -> causal flash attn -> @Wp^T + bp
// B=4 T=2048 C=1024 H=16 HD=64. All matmuls via mfma_f32_16x16x32_bf16 (fp32 accum).
//
// Pipeline: conv_xw (x,Wqkv->bf16 in d_out scratch) -> qkv_gemm (global_load_lds,
// writes Q,K [B,H,T,64] + V transposed [B,H,64,T]) -> attn (swapped-QK^T flash)
// -> conv_wp (Wp->bf16 into dead K region) -> out_gemm (global_load_lds both sides).

using bf16   = __bf16;
using bf16x8 = __attribute__((ext_vector_type(8))) __bf16;
using bf16x4 = __attribute__((ext_vector_type(4))) __bf16;
using f32x4  = __attribute__((ext_vector_type(4))) float;

#define MFMA16(a, b, c) __builtin_amdgcn_mfma_f32_16x16x32_bf16((a), (b), (c), 0, 0, 0)

__device__ __forceinline__ void gll16(const bf16* g, bf16* l) {
    __builtin_amdgcn_global_load_lds(
        (const __attribute__((address_space(1))) void*)(g),
        (__attribute__((address_space(3))) void*)(l),
        16, 0, 0);
}

__device__ __forceinline__ unsigned cvtpk(float lo, float hi) {
    unsigned r;
    asm("v_cvt_pk_bf16_f32 %0, %1, %2" : "=v"(r) : "v"(lo), "v"(hi));
    return r;
}

// ---------------------------------------------------------------------------
// conv_xw: x (8192x1024 f32) -> xb bf16;  Wq|Wk|Wv -> wb bf16 [3072][1024]
// ---------------------------------------------------------------------------
__global__ __launch_bounds__(256) void conv_xw(
    const float* __restrict__ x, const float* __restrict__ Wq,
    const float* __restrict__ Wk, const float* __restrict__ Wv,
    bf16* __restrict__ xb, bf16* __restrict__ wb)
{
    const int n = 2883584;   // 2097152 (x) + 3*262144 (W) float4 chunks
    for (int i = blockIdx.x * 256 + threadIdx.x; i < n; i += gridDim.x * 256) {
        const float* src; bf16* dst; int off;
        if (i < 2097152) { src = x; dst = xb; off = i; }
        else {
            const int j = i - 2097152;
            const int w = j >> 18;
            off = j & 262143;
            src = (w == 0) ? Wq : (w == 1) ? Wk : Wv;
            dst = wb + ((size_t)w << 20);
        }
        const float4 v = *(const float4*)(src + (size_t)off * 4);
        bf16x4 pk = {(bf16)v.x, (bf16)v.y, (bf16)v.z, (bf16)v.w};
        *(bf16x4*)(dst + (size_t)off * 4) = pk;
    }
}

// conv_wp: Wp (1024x1024 f32) -> wpb bf16
__global__ __launch_bounds__(256) void conv_wp(const float* __restrict__ Wp,
                                               bf16* __restrict__ wpb)
{
    const int n = 262144;
    for (int i = blockIdx.x * 256 + threadIdx.x; i < n; i += gridDim.x * 256) {
        const float4 v = *(const float4*)(Wp + (size_t)i * 4);
        bf16x4 pk = {(bf16)v.x, (bf16)v.y, (bf16)v.z, (bf16)v.w};
        *(bf16x4*)(wpb + (size_t)i * 4) = pk;
    }
}

// ---------------------------------------------------------------------------
// qkv_gemm: C[m][n] = sum_k xb[m][k] wb[n][k] (+bias). m97 structure:
// 128x128 tile, BK=64, linear LDS, global_load_lds dwordx4, 2 barriers/K-step.
// Output scatter: Q,K -> [B,H,T,64]; V -> transposed [B,H,64,T].
// ---------------------------------------------------------------------------
__global__ __launch_bounds__(256) void qkv_gemm(
    const bf16* __restrict__ xb, const bf16* __restrict__ wb,
    const float* __restrict__ bq, const float* __restrict__ bk, const float* __restrict__ bv,
    bf16* __restrict__ qws, bf16* __restrict__ kws, bf16* __restrict__ vtws)
{
    __shared__ bf16 As[128][64];
    __shared__ bf16 Bs[128][64];
    const int tid  = threadIdx.x;
    const int lane = tid & 63;
    const int wid  = tid >> 6;
    const int bm   = blockIdx.x;          // 64
    const int bn   = blockIdx.y;          // 24
    const int widx = bn >> 3;
    const float* __restrict__ bias = (widx == 0) ? bq : (widx == 1) ? bk : bv;

    const int wr   = (wid >> 1) << 6;
    const int wc   = (wid & 1) << 6;
    const int lr16 = lane & 15;
    const int lk8  = (lane >> 4) << 3;

    // staging: wave w covers rows w*32..w*32+31 of each tile; 4 calls of 8 rows
    const int lrow = lane >> 3;           // 0..7
    const int lcol = (lane & 7) << 3;     // 0..56
    const bf16* ga = xb + (size_t)(bm * 128 + wid * 32 + lrow) * 1024 + lcol;
    const bf16* gb = wb + (size_t)(bn * 128 + wid * 32 + lrow) * 1024 + lcol;

    f32x4 acc[4][4];
#pragma unroll
    for (int m = 0; m < 4; ++m)
#pragma unroll
        for (int n = 0; n < 4; ++n)
            acc[m][n] = (f32x4){0.f, 0.f, 0.f, 0.f};

    for (int kt = 0; kt < 16; ++kt) {
        const int k0 = kt << 6;
        __syncthreads();
#pragma unroll
        for (int i = 0; i < 4; ++i) {
            gll16(ga + (size_t)i * 8192 + k0, &As[wid * 32 + i * 8][0]);
            gll16(gb + (size_t)i * 8192 + k0, &Bs[wid * 32 + i * 8][0]);
        }
        asm volatile("s_waitcnt vmcnt(0)" ::: "memory");
        __syncthreads();
#pragma unroll
        for (int ks = 0; ks < 2; ++ks) {
            bf16x8 af[4], bfr[4];
#pragma unroll
            for (int m = 0; m < 4; ++m)
                af[m] = *(const bf16x8*)(&As[wr + m * 16 + lr16][ks * 32 + lk8]);
#pragma unroll
            for (int n = 0; n < 4; ++n)
                bfr[n] = *(const bf16x8*)(&Bs[wc + n * 16 + lr16][ks * 32 + lk8]);
#pragma unroll
            for (int m = 0; m < 4; ++m)
#pragma unroll
                for (int n = 0; n < 4; ++n)
                    acc[m][n] = MFMA16(af[m], bfr[n], acc[m][n]);
        }
    }

    const int r4 = (lane >> 4) << 2;
#pragma unroll
    for (int n = 0; n < 4; ++n) {
        const int ncol = bn * 128 + wc + n * 16 + lr16;  // 0..3071
        const int c10  = ncol & 1023;
        const float bia = bias[c10];
        const int h = c10 >> 6, d = c10 & 63;
#pragma unroll
        for (int m = 0; m < 4; ++m) {
#pragma unroll
            for (int r = 0; r < 4; ++r) {
                const int grow = bm * 128 + wr + m * 16 + r4 + r;
                const int b = grow >> 11, t = grow & 2047;
                const bf16 val = (bf16)(acc[m][n][r] + bia);
                if (widx == 2)
                    vtws[((size_t)(b * 16 + h) * 64 + d) * 2048 + t] = val;       // V^T
                else if (widx == 0)
                    qws[((size_t)(b * 16 + h) * 2048 + t) * 64 + d] = val;
                else
                    kws[((size_t)(b * 16 + h) * 2048 + t) * 64 + d] = val;
            }
        }
    }
}

// ---------------------------------------------------------------------------
// attn: causal flash attention, swapped QK^T (S^T = mfma(K,Q)) so softmax is
// lane-local per q-column. 512 blocks x 4 waves; block = q-block pair (s,15-s)
// -> 34 KV tiles each. K/V^T in double-buffered LDS (1 barrier/tile). P packed
// via v_cvt_pk_bf16_f32 -> 8 ds_write_b64 -> 4 ds_read_b128 (per-wave scratch).
// l accumulated by MFMA(ones, P^T). Defer-max THR=64 raw (exp arg <= 11.5).
// ---------------------------------------------------------------------------
__global__ __launch_bounds__(256, 2) void attn_kernel(
    const bf16* __restrict__ q, const bf16* __restrict__ k,
    const bf16* __restrict__ vt, bf16* __restrict__ y)
{
    __shared__ bf16 Ks[2][64][72];
    __shared__ bf16 Vs[2][64][72];
    __shared__ bf16 Ps[4][32][72];
    const int tid  = threadIdx.x;
    const int lane = tid & 63;
    const int wid  = tid >> 6;
    const int lin  = blockIdx.x;
    const int xcd  = lin & 7;
    const int jj   = lin >> 3;
    const int bh   = xcd + ((jj >> 3) << 3);   // 8 heads per XCD
    const int pr   = jj & 7;
    const int bb   = bh >> 4, hh = bh & 15;
    const bf16* __restrict__ qp  = q  + (size_t)bh * 2048 * 64;
    const bf16* __restrict__ kp  = k  + (size_t)bh * 2048 * 64;
    const bf16* __restrict__ vtp = vt + (size_t)bh * 64 * 2048;
    const int lr16 = lane & 15;
    const int g    = lane >> 4;
    const int lk8  = g << 3;
    const int r4   = g << 2;
    const float SCL = 0.18033688f;             // (1/sqrt(64)) * log2(e)
    const int srow = tid >> 3;
    const int scol = (tid & 7) << 3;
    const bf16 one = (bf16)1.0f;
    const bf16x8 onesf = {one, one, one, one, one, one, one, one};

    for (int half = 0; half < 2; ++half) {
        const int s    = half ? (15 - pr) : pr;
        const int q0   = s << 7;
        const int nt   = 2 * s + 2;
        const int wrow = q0 + wid * 32;

        bf16x8 qf[2][2];
#pragma unroll
        for (int mi = 0; mi < 2; ++mi)
#pragma unroll
            for (int dk = 0; dk < 2; ++dk)
                qf[mi][dk] = *(const bf16x8*)(qp + (size_t)(wrow + mi * 16 + lr16) * 64 + dk * 32 + lk8);

        f32x4 ofT[2][4];
        f32x4 lsum[2];
        float mS[2];
#pragma unroll
        for (int mi = 0; mi < 2; ++mi) {
            lsum[mi] = (f32x4){0.f, 0.f, 0.f, 0.f};
            mS[mi]   = -1e30f;
#pragma unroll
            for (int df = 0; df < 4; ++df) ofT[mi][df] = (f32x4){0.f, 0.f, 0.f, 0.f};
        }

        // prologue: stage tile 0 into buf 0
        {
            bf16x8 ka = *(const bf16x8*)(kp + (size_t)srow * 64 + scol);
            bf16x8 kb = *(const bf16x8*)(kp + (size_t)(srow + 32) * 64 + scol);
            bf16x8 va = *(const bf16x8*)(vtp + (size_t)srow * 2048 + scol);
            bf16x8 vb = *(const bf16x8*)(vtp + (size_t)(srow + 32) * 2048 + scol);
            *(bf16x8*)(&Ks[0][srow][scol])      = ka;
            *(bf16x8*)(&Ks[0][srow + 32][scol]) = kb;
            *(bf16x8*)(&Vs[0][srow][scol])      = va;
            *(bf16x8*)(&Vs[0][srow + 32][scol]) = vb;
        }
        int cur = 0;

        for (int t = 0; t < nt; ++t) {
            const int kv0 = t << 6;
            __syncthreads();
            bf16x8 ka, kb, va, vb;
            const bool pf = (t + 1 < nt);
            if (pf) {
                const int kn = kv0 + 64;
                ka = *(const bf16x8*)(kp + (size_t)(kn + srow) * 64 + scol);
                kb = *(const bf16x8*)(kp + (size_t)(kn + srow + 32) * 64 + scol);
                va = *(const bf16x8*)(vtp + (size_t)srow * 2048 + kn + scol);
                vb = *(const bf16x8*)(vtp + (size_t)(srow + 32) * 2048 + kn + scol);
            }
            // ---- S^T = K Q^T : lane holds S^T[k=kv0+16kf+4g+r][q=wrow+16mi+lr16]
            const f32x4 z = (f32x4){0.f, 0.f, 0.f, 0.f};
            f32x4 sT[2][4];
#pragma unroll
            for (int kf = 0; kf < 4; ++kf) {
                const bf16x8 k0f = *(const bf16x8*)(&Ks[cur][kf * 16 + lr16][lk8]);
                const bf16x8 k1f = *(const bf16x8*)(&Ks[cur][kf * 16 + lr16][32 + lk8]);
                sT[0][kf] = MFMA16(k1f, qf[0][1], MFMA16(k0f, qf[0][0], z));
                sT[1][kf] = MFMA16(k1f, qf[1][1], MFMA16(k0f, qf[1][0], z));
            }
            // ---- causal mask ----
#pragma unroll
            for (int mi = 0; mi < 2; ++mi) {
                if (kv0 + 63 > wrow + mi * 16) {
                    const int qq = wrow + mi * 16 + lr16;
#pragma unroll
                    for (int kf = 0; kf < 4; ++kf) {
                        const int kkb = kv0 + kf * 16 + r4;
#pragma unroll
                        for (int r = 0; r < 4; ++r)
                            if (kkb + r > qq) sT[mi][kf][r] = -3.0e38f;
                    }
                }
            }
            // ---- per-q max: in-lane tree + 2 cross-group shuffles ----
            float gmax[2];
#pragma unroll
            for (int mi = 0; mi < 2; ++mi) {
                float a = fmaxf(fmaxf(sT[mi][0][0], sT[mi][0][1]), fmaxf(sT[mi][0][2], sT[mi][0][3]));
                float b = fmaxf(fmaxf(sT[mi][1][0], sT[mi][1][1]), fmaxf(sT[mi][1][2], sT[mi][1][3]));
                float c = fmaxf(fmaxf(sT[mi][2][0], sT[mi][2][1]), fmaxf(sT[mi][2][2], sT[mi][2][3]));
                float d = fmaxf(fmaxf(sT[mi][3][0], sT[mi][3][1]), fmaxf(sT[mi][3][2], sT[mi][3][3]));
                float m = fmaxf(fmaxf(a, b), fmaxf(c, d));
                m = fmaxf(m, __shfl_xor(m, 16));
                m = fmaxf(m, __shfl_xor(m, 32));
                gmax[mi] = m;
            }
            // ---- defer-max rescale ----
            const bool needre = (gmax[0] > mS[0] + 64.0f) | (gmax[1] > mS[1] + 64.0f);
            if (__ballot(needre) != 0ull) {
#pragma unroll
                for (int mi = 0; mi < 2; ++mi) {
                    const float mn   = fmaxf(mS[mi], gmax[mi]);
                    const float corr = exp2f((mS[mi] - mn) * SCL);
                    mS[mi] = mn;
                    lsum[mi][0] *= corr;
#pragma unroll
                    for (int df = 0; df < 4; ++df) ofT[mi][df] *= corr;
                }
            }
            // ---- P = exp2((S-m)*SCL) ----
#pragma unroll
            for (int mi = 0; mi < 2; ++mi)
#pragma unroll
                for (int kf = 0; kf < 4; ++kf)
#pragma unroll
                    for (int r = 0; r < 4; ++r)
                        sT[mi][kf][r] = exp2f((sT[mi][kf][r] - mS[mi]) * SCL);
            // ---- pack pairs (k-consecutive in-lane) -> Ps[q][k] ----
#pragma unroll
            for (int mi = 0; mi < 2; ++mi) {
#pragma unroll
                for (int kf = 0; kf < 4; ++kf) {
                    uint2 u;
                    u.x = cvtpk(sT[mi][kf][0], sT[mi][kf][1]);
                    u.y = cvtpk(sT[mi][kf][2], sT[mi][kf][3]);
                    *(uint2*)(&Ps[wid][mi * 16 + lr16][kf * 16 + r4]) = u;
                }
            }
            asm volatile("s_waitcnt lgkmcnt(0)" ::: "memory");
            __builtin_amdgcn_sched_barrier(0);
            bf16x8 pb[2][2];
#pragma unroll
            for (int mi = 0; mi < 2; ++mi)
#pragma unroll
                for (int ks = 0; ks < 2; ++ks)
                    pb[mi][ks] = *(const bf16x8*)(&Ps[wid][mi * 16 + lr16][ks * 32 + lk8]);
            // ---- O^T += V^T P^T ; l += ones . P^T ----
#pragma unroll
            for (int df = 0; df < 4; ++df) {
                const bf16x8 v0 = *(const bf16x8*)(&Vs[cur][df * 16 + lr16][lk8]);
                const bf16x8 v1 = *(const bf16x8*)(&Vs[cur][df * 16 + lr16][32 + lk8]);
                ofT[0][df] = MFMA16(v0, pb[0][0], ofT[0][df]);
                ofT[0][df] = MFMA16(v1, pb[0][1], ofT[0][df]);
                ofT[1][df] = MFMA16(v0, pb[1][0], ofT[1][df]);
                ofT[1][df] = MFMA16(v1, pb[1][1], ofT[1][df]);
            }
            lsum[0] = MFMA16(onesf, pb[0][0], lsum[0]);
            lsum[0] = MFMA16(onesf, pb[0][1], lsum[0]);
            lsum[1] = MFMA16(onesf, pb[1][0], lsum[1]);
            lsum[1] = MFMA16(onesf, pb[1][1], lsum[1]);
            // ---- write next tile into the other buffer ----
            if (pf) {
                *(bf16x8*)(&Ks[cur ^ 1][srow][scol])      = ka;
                *(bf16x8*)(&Ks[cur ^ 1][srow + 32][scol]) = kb;
                *(bf16x8*)(&Vs[cur ^ 1][srow][scol])      = va;
                *(bf16x8*)(&Vs[cur ^ 1][srow + 32][scol]) = vb;
            }
            cur ^= 1;
        }

        // ---- epilogue: lane holds O^T[d=16df+4g+r][q=wrow+16mi+lr16] ----
#pragma unroll
        for (int mi = 0; mi < 2; ++mi) {
            const float linv = 1.0f / lsum[mi][0];
            const size_t rowb = ((size_t)(bb * 2048 + wrow + mi * 16 + lr16)) * 1024 + hh * 64;
#pragma unroll
            for (int df = 0; df < 4; ++df)
#pragma unroll
                for (int r = 0; r < 4; ++r)
                    y[rowb + df * 16 + r4 + r] = (bf16)(ofT[mi][df][r] * linv);
        }
    }
}

// ---------------------------------------------------------------------------
// out_gemm: out[m][n] = sum_k y[m][k] wpb[n][k] + bp[n]. m97 structure, both
// operands bf16 via global_load_lds. Output fp32.
// ---------------------------------------------------------------------------
__global__ __launch_bounds__(256) void out_gemm(
    const bf16* __restrict__ y, const bf16* __restrict__ wpb,
    const float* __restrict__ bp, float* __restrict__ out)
{
    __shared__ bf16 As[128][64];
    __shared__ bf16 Bs[128][64];
    const int tid  = threadIdx.x;
    const int lane = tid & 63;
    const int wid  = tid >> 6;
    const int bm   = blockIdx.x;
    const int bn   = blockIdx.y;
    const int wr   = (wid >> 1) << 6;
    const int wc   = (wid & 1) << 6;
    const int lr16 = lane & 15;
    const int lk8  = (lane >> 4) << 3;
    const int lrow = lane >> 3;
    const int lcol = (lane & 7) << 3;
    const bf16* ga = y   + (size_t)(bm * 128 + wid * 32 + lrow) * 1024 + lcol;
    const bf16* gb = wpb + (size_t)(bn * 128 + wid * 32 + lrow) * 1024 + lcol;

    f32x4 acc[4][4];
#pragma unroll
    for (int m = 0; m < 4; ++m)
#pragma unroll
        for (int n = 0; n < 4; ++n)
            acc[m][n] = (f32x4){0.f, 0.f, 0.f, 0.f};

    for (int kt = 0; kt < 16; ++kt) {
        const int k0 = kt << 6;
        __syncthreads();
#pragma unroll
        for (int i = 0; i < 4; ++i) {
            gll16(ga + (size_t)i * 8192 + k0, &As[wid * 32 + i * 8][0]);
            gll16(gb + (size_t)i * 8192 + k0, &Bs[wid * 32 + i * 8][0]);
        }
        asm volatile("s_waitcnt vmcnt(0)" ::: "memory");
        __syncthreads();
#pragma unroll
        for (int ks = 0; ks < 2; ++ks) {
            bf16x8 af[4], bfr[4];
#pragma unroll
            for (int m = 0; m < 4; ++m)
                af[m] = *(const bf16x8*)(&As[wr + m * 16 + lr16][ks * 32 + lk8]);
#pragma unroll
            for (int n = 0; n < 4; ++n)
                bfr[n] = *(const bf16x8*)(&Bs[wc + n * 16 + lr16][ks * 32 + lk8]);
#pragma unroll
            for (int m = 0; m < 4; ++m)
#pragma unroll
                for (int n = 0; n < 4; ++n)
                    acc[m][n] = MFMA16(af[m], bfr[n], acc[m][n]);
        }
    }

    const int r4 = (lane >> 4) << 2;
#pragma unroll
    for (int n = 0; n < 4; ++n) {
        const int ncol = bn * 128 + wc + n * 16 + lr16;
        const float bia = bp[ncol];
#pragma unroll
        for (int m = 0; m < 4; ++m) {
#pragma unroll
            for (int r = 0; r < 4; ++r) {
                const int grow = bm * 128 + wr + m * 16 + r4 + r;
                out[(size_t)grow * 1024 + ncol] = acc[m][n][r] + bia;
            }
        }
    }
}

// ---------------------------------------------------------------------------
extern "C" void kernel_launch(void* const* d_in, const int* in_sizes, int n_in,
                              void* d_out, int out_size, void* d_ws, size_t ws_size,
                              hipStream_t stream) {
    const float* x  = (const float*)d_in[0];
    const float* Wq = (const float*)d_in[1];
    const float* bq = (const float*)d_in[2];
    const float* Wk = (const float*)d_in[3];
    const float* bk = (const float*)d_in[4];
    const float* Wv = (const float*)d_in[5];
    const float* bv = (const float*)d_in[6];
    const float* Wp = (const float*)d_in[7];
    const float* bp = (const float*)d_in[8];
    float* out = (float*)d_out;

    char* ws = (char*)d_ws;
    const size_t MB16 = (size_t)16 * 1024 * 1024;
    bf16* qws  = (bf16*)(ws);
    bf16* kws  = (bf16*)(ws + MB16);
    bf16* vtws = (bf16*)(ws + 2 * MB16);
    bf16* yws  = (bf16*)(ws + 3 * MB16);
    bf16* wpb  = kws;                     // K region is dead after attn

    // d_out doubles as scratch for the bf16 copies of x and Wqkv (dead
    // before out_gemm overwrites d_out).
    char* ob = (char*)d_out;
    bf16* xb = (bf16*)(ob);               // 16 MB
    bf16* wb = (bf16*)(ob + MB16);        // 6 MB

    conv_xw<<<2048, 256, 0, stream>>>(x, Wq, Wk, Wv, xb, wb);
    qkv_gemm<<<dim3(64, 24), 256, 0, stream>>>(xb, wb, bq, bk, bv, qws, kws, vtws);
    attn_kernel<<<512, 256, 0, stream>>>(qws, kws, vtws, yws);
    conv_wp<<<256, 256, 0, stream>>>(Wp, wpb);
    out_gemm<<<dim3(64, 8), 256, 0, stream>>>(yws, wpb, bp, out);
}